// Round 7
// baseline (203.670 us; speedup 1.0000x reference)
//
#include <hip/hip_runtime.h>
#include <hip/hip_bf16.h>
#include <hip/hip_fp16.h>

// ZINBDecoder — E=4M edges, D=64.  Outputs concatenated FP32 [mu, disp, pi].
// Round-6 postmortem: latency surgery (DPP, pipelining) was NEUTRAL -> bound
// is scattered-line throughput (L1 miss service). cs/gs fp32 gathers were
// ~38% of scattered L2 lines. Round 7: cs/gs as fp16 tables (20KB+4KB ->
// L1-resident, gathers become L1 hits), 4 tiles/block to amortize weight
// setup, split prep (1-block detect + vectorized convert).

typedef unsigned int u32;
typedef unsigned short u16;
typedef long long i64;
typedef _Float16 v2h __attribute__((ext_vector_type(2)));

__device__ __forceinline__ float us2f(u16 u) { union { u32 i; float f; } v; v.i = ((u32)u) << 16; return v.f; }
__device__ __forceinline__ float lo2f(u32 u) { union { u32 i; float f; } v; v.i = u << 16; return v.f; }
__device__ __forceinline__ float hi2f(u32 u) { union { u32 i; float f; } v; v.i = u & 0xffff0000u; return v.f; }

union H2 { u32 u; __half2 h; v2h v; };

#if defined(__has_builtin)
#if __has_builtin(__builtin_amdgcn_fdot2)
#define HAS_FDOT2 1
#endif
#endif

// quad butterfly add via DPP quad_perm — VALU pipe, no LDS.
__device__ __forceinline__ float qadd(float x) {
    int a = __builtin_amdgcn_mov_dpp(__float_as_int(x), 0xB1, 0xF, 0xF, true);
    float s = x + __int_as_float(a);
    int b = __builtin_amdgcn_mov_dpp(__float_as_int(s), 0x4E, 0xF, 0xF, true);
    return s + __int_as_float(b);
}

// ws layout (bytes):
//   0      : float W32[195] = Wm,Wd,Wp fp32 + biases @192..194
//   800    : int flags[6]: {fc,fg,fcs,fgs,src_i64,dst_i64}
//   1024   : half whalf[192]
//   2048   : half cs_h[10000]   (20000 B)
//   22528  : half gs_h[2000]    (4000 B)
//   28672  : half c_half[640000]  (1280000 B)
//   1308672: half g_half[128000]  (256000 B)   end 1564672
#define FLAGS_OFF 200
#define WHALF_B   1024
#define CSH_B     2048
#define GSH_B     22528
#define CHALF_B   28672
#define GHALF_B   1308672
#define WS_NEED   1564672

// ---------------- prep 1: one-block dtype detection + weights --------------
__global__ __launch_bounds__(256) void zinb_detect1(
    const void* __restrict__ c, const void* __restrict__ g,
    const void* __restrict__ cs, const void* __restrict__ gsp,
    const void* __restrict__ src, const void* __restrict__ dst,
    const void* __restrict__ Wm, const void* __restrict__ bm,
    const void* __restrict__ Wd, const void* __restrict__ bd,
    const void* __restrict__ Wp, const void* __restrict__ bp,
    char* __restrict__ wsb, int ngs)
{
    __shared__ int sf[12];
    int t = threadIdx.x;
    if (t < 12) sf[t] = 0;
    __syncthreads();
    {
        int bad;
        const u32* pc = (const u32*)c;
        bad = 0; for (int i = t; i < 1024; i += 256) { int ex = (pc[i] >> 7) & 0xFF; if (ex >= 135) bad = 1; }
        if (bad) atomicOr(&sf[0], 1);
        const u32* pg = (const u32*)g;
        bad = 0; for (int i = t; i < 1024; i += 256) { int ex = (pg[i] >> 7) & 0xFF; if (ex >= 135) bad = 1; }
        if (bad) atomicOr(&sf[1], 1);
        const u32* ps = (const u32*)cs;
        bad = 0; for (int i = t; i < 1024; i += 256) { int ex = (ps[i] >> 7) & 0xFF; if (ex >= 135) bad = 1; }
        if (bad) atomicOr(&sf[2], 1);
        const u32* pq = (const u32*)gsp;
        int wq = ngs / 2; if (wq > 1000) wq = 1000;
        bad = 0; for (int i = t; i < wq; i += 256) { int ex = (pq[i] >> 7) & 0xFF; if (ex >= 135) bad = 1; }
        if (bad) atomicOr(&sf[3], 1);
        const u32* p4 = (const u32*)src;
        int on = 0, en = 0;
        for (int i = t; i < 1024; i += 256) { if (p4[2 * i + 1] != 0) on = 1; if (p4[2 * i] != 0) en = 1; }
        if (on) atomicOr(&sf[4], 1);
        if (en) atomicOr(&sf[5], 1);
        const u32* p5 = (const u32*)dst;
        on = 0; en = 0;
        for (int i = t; i < 1024; i += 256) { if (p5[2 * i + 1] != 0) on = 1; if (p5[2 * i] != 0) en = 1; }
        if (on) atomicOr(&sf[6], 1);
        if (en) atomicOr(&sf[7], 1);
        if (t < 3) {
            const u32* pw = (t == 0) ? (const u32*)Wm : (t == 1) ? (const u32*)Wd : (const u32*)Wp;
            bad = 0; for (int i = 0; i < 32; ++i) { int ex = (pw[i] >> 7) & 0xFF; if (ex >= 135) bad = 1; }
            if (bad) atomicOr(&sf[8 + t], 1);
        }
    }
    __syncthreads();
    float* W32 = (float*)wsb;
    int w0 = sf[8], w1 = sf[9], w2 = sf[10];
    if (t < 64) {
        W32[t]       = w0 ? ((const float*)Wm)[t] : us2f(((const u16*)Wm)[t]);
        W32[64 + t]  = w1 ? ((const float*)Wd)[t] : us2f(((const u16*)Wd)[t]);
        W32[128 + t] = w2 ? ((const float*)Wp)[t] : us2f(((const u16*)Wp)[t]);
    } else if (t == 64) {
        W32[192] = w0 ? ((const float*)bm)[0] : us2f(((const u16*)bm)[0]);
        W32[193] = w1 ? ((const float*)bd)[0] : us2f(((const u16*)bd)[0]);
        W32[194] = w2 ? ((const float*)bp)[0] : us2f(((const u16*)bp)[0]);
    }
    __syncthreads();
    __half* wh = (__half*)(wsb + WHALF_B);
    if (t < 192) wh[t] = __float2half(W32[t]);
    if (t == 192) {
        int* flg = (int*)wsb + FLAGS_OFF;
        flg[0] = sf[0]; flg[1] = sf[1]; flg[2] = sf[2]; flg[3] = sf[3];
        flg[4] = (!sf[4] && sf[5]) ? 1 : 0;
        flg[5] = (!sf[6] && sf[7]) ? 1 : 0;
    }
}

// ---------------- prep 2: vectorized conversions ---------------------------
__device__ __forceinline__ void cvt4(const void* p, int fp32, int i4, __half* dst) {
    H2 a, b;
    if (fp32) {
        float4 v = ((const float4*)p)[i4 >> 2];
        a.h = __floats2half2_rn(v.x, v.y);
        b.h = __floats2half2_rn(v.z, v.w);
    } else {
        uint2 u = ((const uint2*)p)[i4 >> 2];
        a.h = __floats2half2_rn(lo2f(u.x), hi2f(u.x));
        b.h = __floats2half2_rn(lo2f(u.y), hi2f(u.y));
    }
    uint2 o; o.x = a.u; o.y = b.u;
    ((uint2*)dst)[i4 >> 2] = o;
}

__global__ __launch_bounds__(256) void zinb_convert4(
    const void* __restrict__ c, const void* __restrict__ g,
    const void* __restrict__ cs, const void* __restrict__ gsp,
    char* __restrict__ wsb, int nc, int ng, int ncs, int ngs)
{
    const int* flg = (const int*)wsb + FLAGS_OFF;
    int fc = flg[0], fg = flg[1], fcs = flg[2], fgs = flg[3];
    int t = blockIdx.x * 256 + threadIdx.x;
    int i4 = t * 4;
    __half* ch = (__half*)(wsb + CHALF_B);
    __half* gh = (__half*)(wsb + GHALF_B);
    if (i4 + 3 < nc) cvt4(c, fc, i4, ch);
    else for (int k = 0; k < 4; ++k) if (i4 + k < nc)
        ch[i4 + k] = __float2half(fc ? ((const float*)c)[i4 + k] : us2f(((const u16*)c)[i4 + k]));
    if (i4 + 3 < ng) cvt4(g, fg, i4, gh);
    else for (int k = 0; k < 4; ++k) if (i4 + k < ng)
        gh[i4 + k] = __float2half(fg ? ((const float*)g)[i4 + k] : us2f(((const u16*)g)[i4 + k]));
    __half* csh = (__half*)(wsb + CSH_B);
    __half* gsh = (__half*)(wsb + GSH_B);
    if (t < ncs) csh[t] = __float2half(fcs ? ((const float*)cs)[t] : us2f(((const u16*)cs)[t]));
    if (t < ngs) gsh[t] = __float2half(fgs ? ((const float*)gsp)[t] : us2f(((const u16*)gsp)[t]));
}

// ---- shared inner math ----------------------------------------------------
__device__ __forceinline__ void slice_dot(const uint4& c0, const uint4& c1,
                                          const uint4& g0, const uint4& g1,
                                          const u32* wm, const u32* wd, const u32* wp,
                                          float& am, float& ad, float& ap) {
    u32 cw[8] = {c0.x, c0.y, c0.z, c0.w, c1.x, c1.y, c1.z, c1.w};
    u32 gw[8] = {g0.x, g0.y, g0.z, g0.w, g1.x, g1.y, g1.z, g1.w};
    am = 0.f; ad = 0.f; ap = 0.f;
    #pragma unroll
    for (int j = 0; j < 8; ++j) {
        H2 a, b, pr, w;
        a.u = cw[j]; b.u = gw[j];
        pr.h = __hmul2(a.h, b.h);
#ifdef HAS_FDOT2
        w.u = wm[j]; am = __builtin_amdgcn_fdot2(pr.v, w.v, am, false);
        w.u = wd[j]; ad = __builtin_amdgcn_fdot2(pr.v, w.v, ad, false);
        w.u = wp[j]; ap = __builtin_amdgcn_fdot2(pr.v, w.v, ap, false);
#else
        float2 pf = __half22float2(pr.h);
        H2 t0, t1, t2; t0.u = wm[j]; t1.u = wd[j]; t2.u = wp[j];
        float2 wmf = __half22float2(t0.h);
        float2 wdf = __half22float2(t1.h);
        float2 wpf = __half22float2(t2.h);
        am = fmaf(pf.x, wmf.x, fmaf(pf.y, wmf.y, am));
        ad = fmaf(pf.x, wdf.x, fmaf(pf.y, wdf.y, ad));
        ap = fmaf(pf.x, wpf.x, fmaf(pf.y, wpf.y, ap));
#endif
    }
}

__device__ __forceinline__ void zinb_epilogue(float Sm, float Sd, float Sp,
                                              float cs, float gs,
                                              float bmv, float bdv, float bpv,
                                              float* out, int E, int e) {
    float mu_ = __builtin_amdgcn_rcpf(1.f + __expf(-(Sm + bmv)));
    float pi  = __builtin_amdgcn_rcpf(1.f + __expf(-(Sp + bpv)));
    float xd  = gs * (Sd + bdv);
    float sp  = fmaxf(xd, 0.f) + __logf(1.f + __expf(-fabsf(xd)));
    float disp = fminf(fmaxf(sp, 1e-4f), 1e4f);
    float em  = __expf(gs * mu_) - 1.f;
    float mu  = cs * fminf(fmaxf(em, 1e-5f), 1e6f);
    out[e]         = mu;
    out[E + e]     = disp;
    out[2 * E + e] = pi;
}

// ---------------- main: 4 tiles x 256 edges per block ----------------------
__global__ __launch_bounds__(256) void zinb_fast4(
    const __half* __restrict__ cT, const __half* __restrict__ gT,
    const __half* __restrict__ csh, const __half* __restrict__ gsh,
    const void* __restrict__ src, const void* __restrict__ dst,
    const char* __restrict__ wsb, float* __restrict__ out, int E)
{
    const float* W32 = (const float*)wsb;
    const int* flags = (const int*)wsb + FLAGS_OFF;
    int fs64 = flags[4], fd64 = flags[5];

    int tid = threadIdx.x;
    int q = tid >> 2, l = tid & 3;

    // weights once per block
    const uint4* Wh = (const uint4*)(wsb + WHALF_B);
    uint4 m0 = Wh[l],      m1 = Wh[4 + l];
    uint4 d0 = Wh[8 + l],  d1 = Wh[12 + l];
    uint4 p0 = Wh[16 + l], p1 = Wh[20 + l];
    u32 wm[8] = {m0.x, m0.y, m0.z, m0.w, m1.x, m1.y, m1.z, m1.w};
    u32 wd[8] = {d0.x, d0.y, d0.z, d0.w, d1.x, d1.y, d1.z, d1.w};
    u32 wp[8] = {p0.x, p0.y, p0.z, p0.w, p1.x, p1.y, p1.z, p1.w};
    float bmv = W32[192], bdv = W32[193], bpv = W32[194];

    int blockBase = blockIdx.x * 1024;

    #pragma unroll
    for (int tile = 0; tile < 4; ++tile) {
        int base = blockBase + tile * 256;

        int sI[4], dI[4];
        #pragma unroll
        for (int it = 0; it < 4; ++it) {
            int e = base + it * 64 + q;
            sI[it] = fs64 ? (int)((const i64*)src)[e] : ((const int*)src)[e];
            dI[it] = fd64 ? (int)((const i64*)dst)[e] : ((const int*)dst)[e];
        }
        int s_own = sI[0], d_own = dI[0];
        #pragma unroll
        for (int it = 1; it < 4; ++it)
            if (l == it) { s_own = sI[it]; d_own = dI[it]; }
        float cs = __half2float(csh[s_own]);   // L1-resident (20 KB)
        float gs = __half2float(gsh[d_own]);   // L1-resident (4 KB)

        const uint4* cr = (const uint4*)(cT + (size_t)sI[0] * 64);
        const uint4* gr = (const uint4*)(gT + (size_t)dI[0] * 64);
        uint4 c0 = cr[l], c1 = cr[4 + l];
        uint4 g0 = gr[l], g1 = gr[4 + l];

        float Sm = 0.f, Sd = 0.f, Sp = 0.f;
        #pragma unroll
        for (int it = 0; it < 4; ++it) {
            uint4 nc0, nc1, ng0, ng1;
            if (it < 3) {
                const uint4* crn = (const uint4*)(cT + (size_t)sI[it + 1] * 64);
                const uint4* grn = (const uint4*)(gT + (size_t)dI[it + 1] * 64);
                nc0 = crn[l]; nc1 = crn[4 + l];
                ng0 = grn[l]; ng1 = grn[4 + l];
            }
            float am, ad, ap;
            slice_dot(c0, c1, g0, g1, wm, wd, wp, am, ad, ap);
            am = qadd(am); ad = qadd(ad); ap = qadd(ap);
            if (l == it) { Sm = am; Sd = ad; Sp = ap; }
            if (it < 3) { c0 = nc0; c1 = nc1; g0 = ng0; g1 = ng1; }
        }

        int e_own = base + l * 64 + q;
        zinb_epilogue(Sm, Sd, Sp, cs, gs, bmv, bdv, bpv, out, E, e_own);
    }
}

// ---------------- guarded tail kernel --------------------------------------
__global__ __launch_bounds__(256) void zinb_fast2t(
    const __half* __restrict__ cT, const __half* __restrict__ gT,
    const __half* __restrict__ csh, const __half* __restrict__ gsh,
    const void* __restrict__ src, const void* __restrict__ dst,
    const char* __restrict__ wsb, float* __restrict__ out, int E, int base0)
{
    const float* W32 = (const float*)wsb;
    const int* flags = (const int*)wsb + FLAGS_OFF;
    int fs64 = flags[4], fd64 = flags[5];

    int tid = threadIdx.x;
    int q = tid >> 2, l = tid & 3;
    int base = base0 + blockIdx.x * 256;

    const uint4* Wh = (const uint4*)(wsb + WHALF_B);
    uint4 m0 = Wh[l],      m1 = Wh[4 + l];
    uint4 d0 = Wh[8 + l],  d1 = Wh[12 + l];
    uint4 p0 = Wh[16 + l], p1 = Wh[20 + l];
    u32 wm[8] = {m0.x, m0.y, m0.z, m0.w, m1.x, m1.y, m1.z, m1.w};
    u32 wd[8] = {d0.x, d0.y, d0.z, d0.w, d1.x, d1.y, d1.z, d1.w};
    u32 wp[8] = {p0.x, p0.y, p0.z, p0.w, p1.x, p1.y, p1.z, p1.w};
    float bmv = W32[192], bdv = W32[193], bpv = W32[194];

    float Sm = 0.f, Sd = 0.f, Sp = 0.f;
    int ss = 0, sd2 = 0, se = -1;

    #pragma unroll
    for (int it = 0; it < 4; ++it) {
        int e = base + it * 64 + q;
        bool ok = (e < E);
        int s = 0, d = 0;
        float am = 0.f, ad = 0.f, ap = 0.f;
        if (ok) {
            s = fs64 ? (int)((const i64*)src)[e] : ((const int*)src)[e];
            d = fd64 ? (int)((const i64*)dst)[e] : ((const int*)dst)[e];
            const uint4* cr = (const uint4*)(cT + (size_t)s * 64);
            const uint4* gr = (const uint4*)(gT + (size_t)d * 64);
            uint4 c0 = cr[l], c1 = cr[4 + l];
            uint4 g0 = gr[l], g1 = gr[4 + l];
            slice_dot(c0, c1, g0, g1, wm, wd, wp, am, ad, ap);
        }
        am = qadd(am); ad = qadd(ad); ap = qadd(ap);
        if (l == it && ok) { Sm = am; Sd = ad; Sp = ap; ss = s; sd2 = d; se = e; }
    }

    if (se >= 0)
        zinb_epilogue(Sm, Sd, Sp, __half2float(csh[ss]), __half2float(gsh[sd2]),
                      bmv, bdv, bpv, out, E, se);
}

// ---------------- fallback path (ws too small; round-3 known-good) ---------
__global__ void zinb_detect(const void* c, int nc, const void* g, int ng,
                            const void* cs, int ncs, const void* gsp, int ngs,
                            const void* src, int ns, const void* dst, int nd,
                            int* flags) {
    __shared__ int s_a, s_b;
    int b = blockIdx.x, t = threadIdx.x;
    if (t == 0) { s_a = 0; s_b = 0; }
    __syncthreads();
    if (b < 4) {
        const u32* p; int n;
        if (b == 0)      { p = (const u32*)c;   n = nc;  }
        else if (b == 1) { p = (const u32*)g;   n = ng;  }
        else if (b == 2) { p = (const u32*)cs;  n = ncs; }
        else             { p = (const u32*)gsp; n = ngs; }
        int words = n / 2; if (words > 16384) words = 16384;
        int bad = 0;
        for (int i = t; i < words; i += 256) { int ex = (p[i] >> 7) & 0xFF; if (ex >= 135) bad = 1; }
        if (bad) atomicOr(&s_a, 1);
        __syncthreads();
        if (t == 0) flags[b] = s_a;
    } else {
        const u32* p = (b == 4) ? (const u32*)src : (const u32*)dst;
        int n = (b == 4) ? ns : nd;
        int pairs = (n < 4096) ? n / 2 : 2048;
        int oddnz = 0, evennz = 0;
        for (int i = t; i < pairs; i += 256) {
            if (p[2 * i + 1] != 0) oddnz = 1;
            if (p[2 * i] != 0)     evennz = 1;
        }
        if (oddnz)  atomicOr(&s_a, 1);
        if (evennz) atomicOr(&s_b, 1);
        __syncthreads();
        if (t == 0) flags[b] = (!s_a && s_b) ? 1 : 0;
    }
}

__global__ void zinb_prep_w(const void* Wm, const void* bm, const void* Wd,
                            const void* bd, const void* Wp, const void* bp,
                            float* W) {
    __shared__ int wf[3];
    int t = threadIdx.x;
    if (t < 3) {
        const u32* p = (t == 0) ? (const u32*)Wm : (t == 1) ? (const u32*)Wd : (const u32*)Wp;
        int bad = 0;
        for (int i = 0; i < 32; ++i) { int ex = (p[i] >> 7) & 0xFF; if (ex >= 135) bad = 1; }
        wf[t] = bad;
    }
    __syncthreads();
    if (t < 64) {
        W[t]       = wf[0] ? ((const float*)Wm)[t] : us2f(((const u16*)Wm)[t]);
        W[64 + t]  = wf[1] ? ((const float*)Wd)[t] : us2f(((const u16*)Wd)[t]);
        W[128 + t] = wf[2] ? ((const float*)Wp)[t] : us2f(((const u16*)Wp)[t]);
    } else if (t == 64) {
        W[192] = wf[0] ? ((const float*)bm)[0] : us2f(((const u16*)bm)[0]);
        W[193] = wf[1] ? ((const float*)bd)[0] : us2f(((const u16*)bd)[0]);
        W[194] = wf[2] ? ((const float*)bp)[0] : us2f(((const u16*)bp)[0]);
    }
}

__global__ __launch_bounds__(256) void zinb_main(
    const void* __restrict__ c_feat, const void* __restrict__ g_feat,
    const void* __restrict__ cs_f, const void* __restrict__ gs_f,
    const void* __restrict__ src, const void* __restrict__ dst,
    const float* __restrict__ W, float* __restrict__ out, int E)
{
    int e = blockIdx.x * 256 + threadIdx.x;
    if (e >= E) return;
    const int* flags = (const int*)W + FLAGS_OFF;
    int fc = flags[0], fg = flags[1], fcs = flags[2], fgs = flags[3];
    int fs64 = flags[4], fd64 = flags[5];
    int s = fs64 ? (int)((const i64*)src)[e] : ((const int*)src)[e];
    int d = fd64 ? (int)((const i64*)dst)[e] : ((const int*)dst)[e];
    const char* crow = (const char*)c_feat + (size_t)s * (fc ? 256 : 128);
    const char* grow = (const char*)g_feat + (size_t)d * (fg ? 256 : 128);
    float accm = 0.f, accd = 0.f, accp = 0.f;
    for (int ch = 0; ch < 4; ++ch) {
        float cb[16], gb[16];
        if (fc) {
            const float4* qq = (const float4*)crow;
            #pragma unroll
            for (int j4 = 0; j4 < 4; ++j4) {
                float4 v = qq[ch * 4 + j4];
                cb[j4 * 4] = v.x; cb[j4 * 4 + 1] = v.y; cb[j4 * 4 + 2] = v.z; cb[j4 * 4 + 3] = v.w;
            }
        } else {
            const uint4* qq = (const uint4*)crow;
            #pragma unroll
            for (int j2 = 0; j2 < 2; ++j2) {
                uint4 v = qq[ch * 2 + j2];
                u32 w[4] = {v.x, v.y, v.z, v.w};
                #pragma unroll
                for (int j = 0; j < 4; ++j) {
                    cb[j2 * 8 + j * 2] = lo2f(w[j]); cb[j2 * 8 + j * 2 + 1] = hi2f(w[j]);
                }
            }
        }
        if (fg) {
            const float4* qq = (const float4*)grow;
            #pragma unroll
            for (int j4 = 0; j4 < 4; ++j4) {
                float4 v = qq[ch * 4 + j4];
                gb[j4 * 4] = v.x; gb[j4 * 4 + 1] = v.y; gb[j4 * 4 + 2] = v.z; gb[j4 * 4 + 3] = v.w;
            }
        } else {
            const uint4* qq = (const uint4*)grow;
            #pragma unroll
            for (int j2 = 0; j2 < 2; ++j2) {
                uint4 v = qq[ch * 2 + j2];
                u32 w[4] = {v.x, v.y, v.z, v.w};
                #pragma unroll
                for (int j = 0; j < 4; ++j) {
                    gb[j2 * 8 + j * 2] = lo2f(w[j]); gb[j2 * 8 + j * 2 + 1] = hi2f(w[j]);
                }
            }
        }
        #pragma unroll
        for (int j = 0; j < 16; ++j) {
            int k = ch * 16 + j;
            float h = cb[j] * gb[j];
            accm = fmaf(h, W[k], accm);
            accd = fmaf(h, W[64 + k], accd);
            accp = fmaf(h, W[128 + k], accp);
        }
    }
    float cs = fcs ? ((const float*)cs_f)[s] : us2f(((const u16*)cs_f)[s]);
    float gs = fgs ? ((const float*)gs_f)[d] : us2f(((const u16*)gs_f)[d]);
    float bmv = W[192], bdv = W[193], bpv = W[194];
    float mu_ = 1.f / (1.f + expf(-(accm + bmv)));
    float pi  = 1.f / (1.f + expf(-(accp + bpv)));
    float xd  = gs * (accd + bdv);
    float sp  = fmaxf(xd, 0.f) + log1pf(expf(-fabsf(xd)));
    float disp = fminf(fmaxf(sp, 1e-4f), 1e4f);
    float em  = expf(gs * mu_) - 1.f;
    float mu  = cs * fminf(fmaxf(em, 1e-5f), 1e6f);
    out[e] = mu; out[E + e] = disp; out[2 * E + e] = pi;
}

extern "C" void kernel_launch(void* const* d_in, const int* in_sizes, int n_in,
                              void* d_out, int out_size, void* d_ws, size_t ws_size,
                              hipStream_t stream) {
    const void* c_feat = d_in[0];
    const void* g_feat = d_in[1];
    const void* cs_f   = d_in[2];
    const void* gs_f   = d_in[3];
    const void* src    = d_in[4];
    const void* dst    = d_in[5];
    const void* Wm     = d_in[6];
    const void* bm     = d_in[7];
    const void* Wd     = d_in[8];
    const void* bd     = d_in[9];
    const void* Wp     = d_in[10];
    const void* bp     = d_in[11];

    int E = in_sizes[4];
    int nc = in_sizes[0], ng = in_sizes[1], ncs = in_sizes[2], ngs = in_sizes[3];
    char* wsb = (char*)d_ws;

    if (ws_size >= (size_t)WS_NEED) {
        zinb_detect1<<<1, 256, 0, stream>>>(c_feat, g_feat, cs_f, gs_f, src, dst,
                                            Wm, bm, Wd, bd, Wp, bp, wsb, ngs);
        int nmax4 = ((nc > ng ? nc : ng) + 3) / 4;
        int nmax = nmax4 > ncs ? nmax4 : ncs;
        nmax = nmax > ngs ? nmax : ngs;
        int cvt_blocks = (nmax + 255) / 256;
        zinb_convert4<<<cvt_blocks, 256, 0, stream>>>(c_feat, g_feat, cs_f, gs_f,
                                                      wsb, nc, ng, ncs, ngs);

        const __half* cT  = (const __half*)(wsb + CHALF_B);
        const __half* gT  = (const __half*)(wsb + GHALF_B);
        const __half* csh = (const __half*)(wsb + CSH_B);
        const __half* gsh = (const __half*)(wsb + GSH_B);

        int full1024 = E / 1024;
        if (full1024 > 0)
            zinb_fast4<<<full1024, 256, 0, stream>>>(cT, gT, csh, gsh, src, dst,
                                                     wsb, (float*)d_out, E);
        int rem = E - full1024 * 1024;
        if (rem > 0)
            zinb_fast2t<<<(rem + 255) / 256, 256, 0, stream>>>(
                cT, gT, csh, gsh, src, dst, wsb, (float*)d_out, E, full1024 * 1024);
    } else {
        float* W = (float*)d_ws;
        int* flags = (int*)W + FLAGS_OFF;
        zinb_detect<<<6, 256, 0, stream>>>(c_feat, nc, g_feat, ng, cs_f, ncs,
                                           gs_f, ngs, src, E, dst, in_sizes[5], flags);
        zinb_prep_w<<<1, 256, 0, stream>>>(Wm, bm, Wd, bd, Wp, bp, W);
        int blocks = (E + 255) / 256;
        zinb_main<<<blocks, 256, 0, stream>>>(c_feat, g_feat, cs_f, gs_f, src, dst,
                                              W, (float*)d_out, E);
    }
}

// Round 8
// 182.443 us; speedup vs baseline: 1.1163x; 1.1163x over previous
//
#include <hip/hip_runtime.h>
#include <hip/hip_bf16.h>
#include <hip/hip_fp16.h>

// ZINBDecoder — E=4M edges, D=64.  Outputs concatenated FP32 [mu, disp, pi].
// Round-7 postmortem: cs/gs-as-small-fp16-tables was NEUTRAL — the 1.25MB row
// stream evicts them from L1. Model: bound = L1 miss-service (MSHR) line rate,
// ~0.38 lines/cyc/CU invariant across r4-r7. Round 8: remove cs/gs misses
// entirely by staging both factor tables in LDS (24KB/block), 2048 edges per
// block to amortize staging. Rows stay fp16 (fp8 is precision-borderline).

typedef unsigned int u32;
typedef unsigned short u16;
typedef long long i64;
typedef _Float16 v2h __attribute__((ext_vector_type(2)));

__device__ __forceinline__ float us2f(u16 u) { union { u32 i; float f; } v; v.i = ((u32)u) << 16; return v.f; }
__device__ __forceinline__ float lo2f(u32 u) { union { u32 i; float f; } v; v.i = u << 16; return v.f; }
__device__ __forceinline__ float hi2f(u32 u) { union { u32 i; float f; } v; v.i = u & 0xffff0000u; return v.f; }

union H2 { u32 u; __half2 h; v2h v; };

#if defined(__has_builtin)
#if __has_builtin(__builtin_amdgcn_fdot2)
#define HAS_FDOT2 1
#endif
#endif

__device__ __forceinline__ float qadd(float x) {
    int a = __builtin_amdgcn_mov_dpp(__float_as_int(x), 0xB1, 0xF, 0xF, true);
    float s = x + __int_as_float(a);
    int b = __builtin_amdgcn_mov_dpp(__float_as_int(s), 0x4E, 0xF, 0xF, true);
    return s + __int_as_float(b);
}

// ws layout (bytes):
//   0      : float W32[195] ; 800: int flags[6] ; 1024: half whalf[192]
//   2048   : half cs_h[<=10240]  (20480 B region)
//   22528  : half gs_h[<=3072]   (6144 B region)
//   28672  : half c_half[640000]
//   1308672: half g_half[128000]   end 1564672
#define FLAGS_OFF 200
#define WHALF_B   1024
#define CSH_B     2048
#define GSH_B     22528
#define CHALF_B   28672
#define GHALF_B   1308672
#define WS_NEED   1564672

#define EDGES_PER_BLOCK 2048

// ---------------- prep 1: one-block dtype detection + weights --------------
__global__ __launch_bounds__(256) void zinb_detect1(
    const void* __restrict__ c, const void* __restrict__ g,
    const void* __restrict__ cs, const void* __restrict__ gsp,
    const void* __restrict__ src, const void* __restrict__ dst,
    const void* __restrict__ Wm, const void* __restrict__ bm,
    const void* __restrict__ Wd, const void* __restrict__ bd,
    const void* __restrict__ Wp, const void* __restrict__ bp,
    char* __restrict__ wsb, int ngs)
{
    __shared__ int sf[12];
    int t = threadIdx.x;
    if (t < 12) sf[t] = 0;
    __syncthreads();
    {
        int bad;
        const u32* pc = (const u32*)c;
        bad = 0; for (int i = t; i < 1024; i += 256) { int ex = (pc[i] >> 7) & 0xFF; if (ex >= 135) bad = 1; }
        if (bad) atomicOr(&sf[0], 1);
        const u32* pg = (const u32*)g;
        bad = 0; for (int i = t; i < 1024; i += 256) { int ex = (pg[i] >> 7) & 0xFF; if (ex >= 135) bad = 1; }
        if (bad) atomicOr(&sf[1], 1);
        const u32* ps = (const u32*)cs;
        bad = 0; for (int i = t; i < 1024; i += 256) { int ex = (ps[i] >> 7) & 0xFF; if (ex >= 135) bad = 1; }
        if (bad) atomicOr(&sf[2], 1);
        const u32* pq = (const u32*)gsp;
        int wq = ngs / 2; if (wq > 1000) wq = 1000;
        bad = 0; for (int i = t; i < wq; i += 256) { int ex = (pq[i] >> 7) & 0xFF; if (ex >= 135) bad = 1; }
        if (bad) atomicOr(&sf[3], 1);
        const u32* p4 = (const u32*)src;
        int on = 0, en = 0;
        for (int i = t; i < 1024; i += 256) { if (p4[2 * i + 1] != 0) on = 1; if (p4[2 * i] != 0) en = 1; }
        if (on) atomicOr(&sf[4], 1);
        if (en) atomicOr(&sf[5], 1);
        const u32* p5 = (const u32*)dst;
        on = 0; en = 0;
        for (int i = t; i < 1024; i += 256) { if (p5[2 * i + 1] != 0) on = 1; if (p5[2 * i] != 0) en = 1; }
        if (on) atomicOr(&sf[6], 1);
        if (en) atomicOr(&sf[7], 1);
        if (t < 3) {
            const u32* pw = (t == 0) ? (const u32*)Wm : (t == 1) ? (const u32*)Wd : (const u32*)Wp;
            bad = 0; for (int i = 0; i < 32; ++i) { int ex = (pw[i] >> 7) & 0xFF; if (ex >= 135) bad = 1; }
            if (bad) atomicOr(&sf[8 + t], 1);
        }
    }
    __syncthreads();
    float* W32 = (float*)wsb;
    int w0 = sf[8], w1 = sf[9], w2 = sf[10];
    if (t < 64) {
        W32[t]       = w0 ? ((const float*)Wm)[t] : us2f(((const u16*)Wm)[t]);
        W32[64 + t]  = w1 ? ((const float*)Wd)[t] : us2f(((const u16*)Wd)[t]);
        W32[128 + t] = w2 ? ((const float*)Wp)[t] : us2f(((const u16*)Wp)[t]);
    } else if (t == 64) {
        W32[192] = w0 ? ((const float*)bm)[0] : us2f(((const u16*)bm)[0]);
        W32[193] = w1 ? ((const float*)bd)[0] : us2f(((const u16*)bd)[0]);
        W32[194] = w2 ? ((const float*)bp)[0] : us2f(((const u16*)bp)[0]);
    }
    __syncthreads();
    __half* wh = (__half*)(wsb + WHALF_B);
    if (t < 192) wh[t] = __float2half(W32[t]);
    if (t == 192) {
        int* flg = (int*)wsb + FLAGS_OFF;
        flg[0] = sf[0]; flg[1] = sf[1]; flg[2] = sf[2]; flg[3] = sf[3];
        flg[4] = (!sf[4] && sf[5]) ? 1 : 0;
        flg[5] = (!sf[6] && sf[7]) ? 1 : 0;
    }
}

// ---------------- prep 2: vectorized conversions ---------------------------
__device__ __forceinline__ void cvt4(const void* p, int fp32, int i4, __half* dst) {
    H2 a, b;
    if (fp32) {
        float4 v = ((const float4*)p)[i4 >> 2];
        a.h = __floats2half2_rn(v.x, v.y);
        b.h = __floats2half2_rn(v.z, v.w);
    } else {
        uint2 u = ((const uint2*)p)[i4 >> 2];
        a.h = __floats2half2_rn(lo2f(u.x), hi2f(u.x));
        b.h = __floats2half2_rn(lo2f(u.y), hi2f(u.y));
    }
    uint2 o; o.x = a.u; o.y = b.u;
    ((uint2*)dst)[i4 >> 2] = o;
}

__global__ __launch_bounds__(256) void zinb_convert4(
    const void* __restrict__ c, const void* __restrict__ g,
    const void* __restrict__ cs, const void* __restrict__ gsp,
    char* __restrict__ wsb, int nc, int ng, int ncs, int ngs)
{
    const int* flg = (const int*)wsb + FLAGS_OFF;
    int fc = flg[0], fg = flg[1], fcs = flg[2], fgs = flg[3];
    int t = blockIdx.x * 256 + threadIdx.x;
    int i4 = t * 4;
    __half* ch = (__half*)(wsb + CHALF_B);
    __half* gh = (__half*)(wsb + GHALF_B);
    if (i4 + 3 < nc) cvt4(c, fc, i4, ch);
    else for (int k = 0; k < 4; ++k) if (i4 + k < nc)
        ch[i4 + k] = __float2half(fc ? ((const float*)c)[i4 + k] : us2f(((const u16*)c)[i4 + k]));
    if (i4 + 3 < ng) cvt4(g, fg, i4, gh);
    else for (int k = 0; k < 4; ++k) if (i4 + k < ng)
        gh[i4 + k] = __float2half(fg ? ((const float*)g)[i4 + k] : us2f(((const u16*)g)[i4 + k]));
    __half* csh = (__half*)(wsb + CSH_B);
    __half* gsh = (__half*)(wsb + GSH_B);
    if (t < ncs) csh[t] = __float2half(fcs ? ((const float*)cs)[t] : us2f(((const u16*)cs)[t]));
    if (t < ngs) gsh[t] = __float2half(fgs ? ((const float*)gsp)[t] : us2f(((const u16*)gsp)[t]));
}

// ---- shared inner math ----------------------------------------------------
__device__ __forceinline__ void slice_dot(const uint4& c0, const uint4& c1,
                                          const uint4& g0, const uint4& g1,
                                          const u32* wm, const u32* wd, const u32* wp,
                                          float& am, float& ad, float& ap) {
    u32 cw[8] = {c0.x, c0.y, c0.z, c0.w, c1.x, c1.y, c1.z, c1.w};
    u32 gw[8] = {g0.x, g0.y, g0.z, g0.w, g1.x, g1.y, g1.z, g1.w};
    am = 0.f; ad = 0.f; ap = 0.f;
    #pragma unroll
    for (int j = 0; j < 8; ++j) {
        H2 a, b, pr, w;
        a.u = cw[j]; b.u = gw[j];
        pr.h = __hmul2(a.h, b.h);
#ifdef HAS_FDOT2
        w.u = wm[j]; am = __builtin_amdgcn_fdot2(pr.v, w.v, am, false);
        w.u = wd[j]; ad = __builtin_amdgcn_fdot2(pr.v, w.v, ad, false);
        w.u = wp[j]; ap = __builtin_amdgcn_fdot2(pr.v, w.v, ap, false);
#else
        float2 pf = __half22float2(pr.h);
        H2 t0, t1, t2; t0.u = wm[j]; t1.u = wd[j]; t2.u = wp[j];
        float2 wmf = __half22float2(t0.h);
        float2 wdf = __half22float2(t1.h);
        float2 wpf = __half22float2(t2.h);
        am = fmaf(pf.x, wmf.x, fmaf(pf.y, wmf.y, am));
        ad = fmaf(pf.x, wdf.x, fmaf(pf.y, wdf.y, ad));
        ap = fmaf(pf.x, wpf.x, fmaf(pf.y, wpf.y, ap));
#endif
    }
}

__device__ __forceinline__ void zinb_epilogue(float Sm, float Sd, float Sp,
                                              float cs, float gs,
                                              float bmv, float bdv, float bpv,
                                              float* out, int E, int e) {
    float mu_ = __builtin_amdgcn_rcpf(1.f + __expf(-(Sm + bmv)));
    float pi  = __builtin_amdgcn_rcpf(1.f + __expf(-(Sp + bpv)));
    float xd  = gs * (Sd + bdv);
    float sp  = fmaxf(xd, 0.f) + __logf(1.f + __expf(-fabsf(xd)));
    float disp = fminf(fmaxf(sp, 1e-4f), 1e4f);
    float em  = __expf(gs * mu_) - 1.f;
    float mu  = cs * fminf(fmaxf(em, 1e-5f), 1e6f);
    out[e]         = mu;
    out[E + e]     = disp;
    out[2 * E + e] = pi;
}

// ---------------- main: LDS-staged factors, 8 tiles x 256 edges ------------
__global__ __launch_bounds__(256) void zinb_fast5(
    const __half* __restrict__ cT, const __half* __restrict__ gT,
    const __half* __restrict__ csh, const __half* __restrict__ gsh,
    const void* __restrict__ src, const void* __restrict__ dst,
    const char* __restrict__ wsb, float* __restrict__ out, int E,
    int ncs, int ngs)
{
    __shared__ __align__(16) __half s_cs[10240];
    __shared__ __align__(16) __half s_gs[2560];
    {
        int n4 = (ncs + 7) / 8;                 // uint4 = 8 halves
        const uint4* s4 = (const uint4*)csh;
        uint4* d4 = (uint4*)s_cs;
        for (int i = threadIdx.x; i < n4; i += 256) d4[i] = s4[i];
        int m4 = (ngs + 7) / 8;
        const uint4* s5 = (const uint4*)gsh;
        uint4* d5 = (uint4*)s_gs;
        for (int i = threadIdx.x; i < m4; i += 256) d5[i] = s5[i];
    }
    __syncthreads();

    const float* W32 = (const float*)wsb;
    const int* flags = (const int*)wsb + FLAGS_OFF;
    int fs64 = flags[4], fd64 = flags[5];

    int tid = threadIdx.x;
    int q = tid >> 2, l = tid & 3;

    const uint4* Wh = (const uint4*)(wsb + WHALF_B);
    uint4 m0 = Wh[l],      m1 = Wh[4 + l];
    uint4 d0 = Wh[8 + l],  d1 = Wh[12 + l];
    uint4 p0 = Wh[16 + l], p1 = Wh[20 + l];
    u32 wm[8] = {m0.x, m0.y, m0.z, m0.w, m1.x, m1.y, m1.z, m1.w};
    u32 wd[8] = {d0.x, d0.y, d0.z, d0.w, d1.x, d1.y, d1.z, d1.w};
    u32 wp[8] = {p0.x, p0.y, p0.z, p0.w, p1.x, p1.y, p1.z, p1.w};
    float bmv = W32[192], bdv = W32[193], bpv = W32[194];

    int blockBase = blockIdx.x * EDGES_PER_BLOCK;

    for (int tile = 0; tile < EDGES_PER_BLOCK / 256; ++tile) {
        int base = blockBase + tile * 256;

        int sI[4], dI[4];
        #pragma unroll
        for (int it = 0; it < 4; ++it) {
            int e = base + it * 64 + q;
            sI[it] = fs64 ? (int)((const i64*)src)[e] : ((const int*)src)[e];
            dI[it] = fd64 ? (int)((const i64*)dst)[e] : ((const int*)dst)[e];
        }
        int s_own = sI[0], d_own = dI[0];
        #pragma unroll
        for (int it = 1; it < 4; ++it)
            if (l == it) { s_own = sI[it]; d_own = dI[it]; }
        float cs = __half2float(s_cs[s_own]);   // LDS — no L1/MSHR traffic
        float gs = __half2float(s_gs[d_own]);

        const uint4* cr = (const uint4*)(cT + (size_t)sI[0] * 64);
        const uint4* gr = (const uint4*)(gT + (size_t)dI[0] * 64);
        uint4 c0 = cr[l], c1 = cr[4 + l];
        uint4 g0 = gr[l], g1 = gr[4 + l];

        float Sm = 0.f, Sd = 0.f, Sp = 0.f;
        #pragma unroll
        for (int it = 0; it < 4; ++it) {
            uint4 nc0, nc1, ng0, ng1;
            if (it < 3) {
                const uint4* crn = (const uint4*)(cT + (size_t)sI[it + 1] * 64);
                const uint4* grn = (const uint4*)(gT + (size_t)dI[it + 1] * 64);
                nc0 = crn[l]; nc1 = crn[4 + l];
                ng0 = grn[l]; ng1 = grn[4 + l];
            }
            float am, ad, ap;
            slice_dot(c0, c1, g0, g1, wm, wd, wp, am, ad, ap);
            am = qadd(am); ad = qadd(ad); ap = qadd(ap);
            if (l == it) { Sm = am; Sd = ad; Sp = ap; }
            if (it < 3) { c0 = nc0; c1 = nc1; g0 = ng0; g1 = ng1; }
        }

        int e_own = base + l * 64 + q;
        zinb_epilogue(Sm, Sd, Sp, cs, gs, bmv, bdv, bpv, out, E, e_own);
    }
}

// ---------------- guarded tail / generic kernel ----------------------------
__global__ __launch_bounds__(256) void zinb_fast2t(
    const __half* __restrict__ cT, const __half* __restrict__ gT,
    const __half* __restrict__ csh, const __half* __restrict__ gsh,
    const void* __restrict__ src, const void* __restrict__ dst,
    const char* __restrict__ wsb, float* __restrict__ out, int E, int base0)
{
    const float* W32 = (const float*)wsb;
    const int* flags = (const int*)wsb + FLAGS_OFF;
    int fs64 = flags[4], fd64 = flags[5];

    int tid = threadIdx.x;
    int q = tid >> 2, l = tid & 3;
    int base = base0 + blockIdx.x * 256;

    const uint4* Wh = (const uint4*)(wsb + WHALF_B);
    uint4 m0 = Wh[l],      m1 = Wh[4 + l];
    uint4 d0 = Wh[8 + l],  d1 = Wh[12 + l];
    uint4 p0 = Wh[16 + l], p1 = Wh[20 + l];
    u32 wm[8] = {m0.x, m0.y, m0.z, m0.w, m1.x, m1.y, m1.z, m1.w};
    u32 wd[8] = {d0.x, d0.y, d0.z, d0.w, d1.x, d1.y, d1.z, d1.w};
    u32 wp[8] = {p0.x, p0.y, p0.z, p0.w, p1.x, p1.y, p1.z, p1.w};
    float bmv = W32[192], bdv = W32[193], bpv = W32[194];

    float Sm = 0.f, Sd = 0.f, Sp = 0.f;
    int ss = 0, sd2 = 0, se = -1;

    #pragma unroll
    for (int it = 0; it < 4; ++it) {
        int e = base + it * 64 + q;
        bool ok = (e < E);
        int s = 0, d = 0;
        float am = 0.f, ad = 0.f, ap = 0.f;
        if (ok) {
            s = fs64 ? (int)((const i64*)src)[e] : ((const int*)src)[e];
            d = fd64 ? (int)((const i64*)dst)[e] : ((const int*)dst)[e];
            const uint4* cr = (const uint4*)(cT + (size_t)s * 64);
            const uint4* gr = (const uint4*)(gT + (size_t)d * 64);
            uint4 c0 = cr[l], c1 = cr[4 + l];
            uint4 g0 = gr[l], g1 = gr[4 + l];
            slice_dot(c0, c1, g0, g1, wm, wd, wp, am, ad, ap);
        }
        am = qadd(am); ad = qadd(ad); ap = qadd(ap);
        if (l == it && ok) { Sm = am; Sd = ad; Sp = ap; ss = s; sd2 = d; se = e; }
    }

    if (se >= 0)
        zinb_epilogue(Sm, Sd, Sp, __half2float(csh[ss]), __half2float(gsh[sd2]),
                      bmv, bdv, bpv, out, E, se);
}

// ---------------- fallback path (ws too small; round-3 known-good) ---------
__global__ void zinb_detect(const void* c, int nc, const void* g, int ng,
                            const void* cs, int ncs, const void* gsp, int ngs,
                            const void* src, int ns, const void* dst, int nd,
                            int* flags) {
    __shared__ int s_a, s_b;
    int b = blockIdx.x, t = threadIdx.x;
    if (t == 0) { s_a = 0; s_b = 0; }
    __syncthreads();
    if (b < 4) {
        const u32* p; int n;
        if (b == 0)      { p = (const u32*)c;   n = nc;  }
        else if (b == 1) { p = (const u32*)g;   n = ng;  }
        else if (b == 2) { p = (const u32*)cs;  n = ncs; }
        else             { p = (const u32*)gsp; n = ngs; }
        int words = n / 2; if (words > 16384) words = 16384;
        int bad = 0;
        for (int i = t; i < words; i += 256) { int ex = (p[i] >> 7) & 0xFF; if (ex >= 135) bad = 1; }
        if (bad) atomicOr(&s_a, 1);
        __syncthreads();
        if (t == 0) flags[b] = s_a;
    } else {
        const u32* p = (b == 4) ? (const u32*)src : (const u32*)dst;
        int n = (b == 4) ? ns : nd;
        int pairs = (n < 4096) ? n / 2 : 2048;
        int oddnz = 0, evennz = 0;
        for (int i = t; i < pairs; i += 256) {
            if (p[2 * i + 1] != 0) oddnz = 1;
            if (p[2 * i] != 0)     evennz = 1;
        }
        if (oddnz)  atomicOr(&s_a, 1);
        if (evennz) atomicOr(&s_b, 1);
        __syncthreads();
        if (t == 0) flags[b] = (!s_a && s_b) ? 1 : 0;
    }
}

__global__ void zinb_prep_w(const void* Wm, const void* bm, const void* Wd,
                            const void* bd, const void* Wp, const void* bp,
                            float* W) {
    __shared__ int wf[3];
    int t = threadIdx.x;
    if (t < 3) {
        const u32* p = (t == 0) ? (const u32*)Wm : (t == 1) ? (const u32*)Wd : (const u32*)Wp;
        int bad = 0;
        for (int i = 0; i < 32; ++i) { int ex = (p[i] >> 7) & 0xFF; if (ex >= 135) bad = 1; }
        wf[t] = bad;
    }
    __syncthreads();
    if (t < 64) {
        W[t]       = wf[0] ? ((const float*)Wm)[t] : us2f(((const u16*)Wm)[t]);
        W[64 + t]  = wf[1] ? ((const float*)Wd)[t] : us2f(((const u16*)Wd)[t]);
        W[128 + t] = wf[2] ? ((const float*)Wp)[t] : us2f(((const u16*)Wp)[t]);
    } else if (t == 64) {
        W[192] = wf[0] ? ((const float*)bm)[0] : us2f(((const u16*)bm)[0]);
        W[193] = wf[1] ? ((const float*)bd)[0] : us2f(((const u16*)bd)[0]);
        W[194] = wf[2] ? ((const float*)bp)[0] : us2f(((const u16*)bp)[0]);
    }
}

__global__ __launch_bounds__(256) void zinb_main(
    const void* __restrict__ c_feat, const void* __restrict__ g_feat,
    const void* __restrict__ cs_f, const void* __restrict__ gs_f,
    const void* __restrict__ src, const void* __restrict__ dst,
    const float* __restrict__ W, float* __restrict__ out, int E)
{
    int e = blockIdx.x * 256 + threadIdx.x;
    if (e >= E) return;
    const int* flags = (const int*)W + FLAGS_OFF;
    int fc = flags[0], fg = flags[1], fcs = flags[2], fgs = flags[3];
    int fs64 = flags[4], fd64 = flags[5];
    int s = fs64 ? (int)((const i64*)src)[e] : ((const int*)src)[e];
    int d = fd64 ? (int)((const i64*)dst)[e] : ((const int*)dst)[e];
    const char* crow = (const char*)c_feat + (size_t)s * (fc ? 256 : 128);
    const char* grow = (const char*)g_feat + (size_t)d * (fg ? 256 : 128);
    float accm = 0.f, accd = 0.f, accp = 0.f;
    for (int ch = 0; ch < 4; ++ch) {
        float cb[16], gb[16];
        if (fc) {
            const float4* qq = (const float4*)crow;
            #pragma unroll
            for (int j4 = 0; j4 < 4; ++j4) {
                float4 v = qq[ch * 4 + j4];
                cb[j4 * 4] = v.x; cb[j4 * 4 + 1] = v.y; cb[j4 * 4 + 2] = v.z; cb[j4 * 4 + 3] = v.w;
            }
        } else {
            const uint4* qq = (const uint4*)crow;
            #pragma unroll
            for (int j2 = 0; j2 < 2; ++j2) {
                uint4 v = qq[ch * 2 + j2];
                u32 w[4] = {v.x, v.y, v.z, v.w};
                #pragma unroll
                for (int j = 0; j < 4; ++j) {
                    cb[j2 * 8 + j * 2] = lo2f(w[j]); cb[j2 * 8 + j * 2 + 1] = hi2f(w[j]);
                }
            }
        }
        if (fg) {
            const float4* qq = (const float4*)grow;
            #pragma unroll
            for (int j4 = 0; j4 < 4; ++j4) {
                float4 v = qq[ch * 4 + j4];
                gb[j4 * 4] = v.x; gb[j4 * 4 + 1] = v.y; gb[j4 * 4 + 2] = v.z; gb[j4 * 4 + 3] = v.w;
            }
        } else {
            const uint4* qq = (const uint4*)grow;
            #pragma unroll
            for (int j2 = 0; j2 < 2; ++j2) {
                uint4 v = qq[ch * 2 + j2];
                u32 w[4] = {v.x, v.y, v.z, v.w};
                #pragma unroll
                for (int j = 0; j < 4; ++j) {
                    gb[j2 * 8 + j * 2] = lo2f(w[j]); gb[j2 * 8 + j * 2 + 1] = hi2f(w[j]);
                }
            }
        }
        #pragma unroll
        for (int j = 0; j < 16; ++j) {
            int k = ch * 16 + j;
            float h = cb[j] * gb[j];
            accm = fmaf(h, W[k], accm);
            accd = fmaf(h, W[64 + k], accd);
            accp = fmaf(h, W[128 + k], accp);
        }
    }
    float cs = fcs ? ((const float*)cs_f)[s] : us2f(((const u16*)cs_f)[s]);
    float gs = fgs ? ((const float*)gs_f)[d] : us2f(((const u16*)gs_f)[d]);
    float bmv = W[192], bdv = W[193], bpv = W[194];
    float mu_ = 1.f / (1.f + expf(-(accm + bmv)));
    float pi  = 1.f / (1.f + expf(-(accp + bpv)));
    float xd  = gs * (accd + bdv);
    float sp  = fmaxf(xd, 0.f) + log1pf(expf(-fabsf(xd)));
    float disp = fminf(fmaxf(sp, 1e-4f), 1e4f);
    float em  = expf(gs * mu_) - 1.f;
    float mu  = cs * fminf(fmaxf(em, 1e-5f), 1e6f);
    out[e] = mu; out[E + e] = disp; out[2 * E + e] = pi;
}

extern "C" void kernel_launch(void* const* d_in, const int* in_sizes, int n_in,
                              void* d_out, int out_size, void* d_ws, size_t ws_size,
                              hipStream_t stream) {
    const void* c_feat = d_in[0];
    const void* g_feat = d_in[1];
    const void* cs_f   = d_in[2];
    const void* gs_f   = d_in[3];
    const void* src    = d_in[4];
    const void* dst    = d_in[5];
    const void* Wm     = d_in[6];
    const void* bm     = d_in[7];
    const void* Wd     = d_in[8];
    const void* bd     = d_in[9];
    const void* Wp     = d_in[10];
    const void* bp     = d_in[11];

    int E = in_sizes[4];
    int nc = in_sizes[0], ng = in_sizes[1], ncs = in_sizes[2], ngs = in_sizes[3];
    char* wsb = (char*)d_ws;

    if (ws_size >= (size_t)WS_NEED && ncs <= 10232 && ngs <= 2552) {
        zinb_detect1<<<1, 256, 0, stream>>>(c_feat, g_feat, cs_f, gs_f, src, dst,
                                            Wm, bm, Wd, bd, Wp, bp, wsb, ngs);
        int nmax4 = ((nc > ng ? nc : ng) + 3) / 4;
        int nmax = nmax4 > ncs ? nmax4 : ncs;
        nmax = nmax > ngs ? nmax : ngs;
        int cvt_blocks = (nmax + 255) / 256;
        zinb_convert4<<<cvt_blocks, 256, 0, stream>>>(c_feat, g_feat, cs_f, gs_f,
                                                      wsb, nc, ng, ncs, ngs);

        const __half* cT  = (const __half*)(wsb + CHALF_B);
        const __half* gT  = (const __half*)(wsb + GHALF_B);
        const __half* csh = (const __half*)(wsb + CSH_B);
        const __half* gsh = (const __half*)(wsb + GSH_B);

        int fullB = E / EDGES_PER_BLOCK;
        if (fullB > 0)
            zinb_fast5<<<fullB, 256, 0, stream>>>(cT, gT, csh, gsh, src, dst,
                                                  wsb, (float*)d_out, E, ncs, ngs);
        int rem = E - fullB * EDGES_PER_BLOCK;
        if (rem > 0)
            zinb_fast2t<<<(rem + 255) / 256, 256, 0, stream>>>(
                cT, gT, csh, gsh, src, dst, wsb, (float*)d_out, E,
                fullB * EDGES_PER_BLOCK);
    } else if (ws_size >= (size_t)WS_NEED) {
        zinb_detect1<<<1, 256, 0, stream>>>(c_feat, g_feat, cs_f, gs_f, src, dst,
                                            Wm, bm, Wd, bd, Wp, bp, wsb, ngs);
        int nmax4 = ((nc > ng ? nc : ng) + 3) / 4;
        int nmax = nmax4 > ncs ? nmax4 : ncs;
        nmax = nmax > ngs ? nmax : ngs;
        int cvt_blocks = (nmax + 255) / 256;
        zinb_convert4<<<cvt_blocks, 256, 0, stream>>>(c_feat, g_feat, cs_f, gs_f,
                                                      wsb, nc, ng, ncs, ngs);
        const __half* cT  = (const __half*)(wsb + CHALF_B);
        const __half* gT  = (const __half*)(wsb + GHALF_B);
        const __half* csh = (const __half*)(wsb + CSH_B);
        const __half* gsh = (const __half*)(wsb + GSH_B);
        zinb_fast2t<<<(E + 255) / 256, 256, 0, stream>>>(
            cT, gT, csh, gsh, src, dst, wsb, (float*)d_out, E, 0);
    } else {
        float* W = (float*)d_ws;
        int* flags = (int*)W + FLAGS_OFF;
        zinb_detect<<<6, 256, 0, stream>>>(c_feat, nc, g_feat, ng, cs_f, ncs,
                                           gs_f, ngs, src, E, dst, in_sizes[5], flags);
        zinb_prep_w<<<1, 256, 0, stream>>>(Wm, bm, Wd, bd, Wp, bp, W);
        int blocks = (E + 255) / 256;
        zinb_main<<<blocks, 256, 0, stream>>>(c_feat, g_feat, cs_f, gs_f, src, dst,
                                              W, (float*)d_out, E);
    }
}